// Round 9
// baseline (182.490 us; speedup 1.0000x reference)
//
#include <hip/hip_runtime.h>
#include <hip/hip_bf16.h>

// B=2, T=2048, C=1024, H=16, D=64. Inputs/outputs FLOAT32; compute bf16 MFMA.
// R16: attn = 2-wave blocks (128 thr), 64-row strip, 32 q-rows/wave.
//  R15 post-mortem: halved LDS-reads/MFMA was real but eaten by load
//  imbalance (512 blocks = exactly 2/CU resident, no refill slack ->
//  makespan ~1.9x mean). R16 keeps the read-sharing AND the balance:
//  1024 blocks (64-row strips, long-first) with 2-of-8-waves resident slack,
//  each wave computing two 16-row q-groups (K/V frag read once, feeds both).
//  KVBLK=128 dbuf (64KB, 2 blocks/CU); staging = 16 gll16/thread/tile with
//  pre-swizzled global source (K row-perm + V XOR-16 folded into src addr).
//  Schedule/softmax identical to R14: {vmcnt(0); barrier; stage(jt+1);
//  compute}; p = v_exp_f32(S + C-in bias); q pre-scaled log2e/8.
// gemm_bt/prep unchanged (R11 known-good).

typedef __bf16 bf16x8 __attribute__((ext_vector_type(8)));
typedef float  f32x4  __attribute__((ext_vector_type(4)));
#define BF16 __hip_bfloat16

constexpr int Bb = 2, Tt = 2048, Cc = 1024, Hh = 16, Dd = 64;
constexpr float NEG_INF = -1e30f;
constexpr float Q_SCALE = 0.18033688011112042f;   // (1/8) * log2(e)
constexpr float EXP2_BIAS = 17.312340490667562f;  // 12 * log2(e)

__device__ __forceinline__ f32x4 mfma16(bf16x8 a, bf16x8 b, f32x4 c) {
  return __builtin_amdgcn_mfma_f32_16x16x32_bf16(a, b, c, 0, 0, 0);
}

// raw v_exp_f32 (exp2): 1 trans instr, no OCML denormal guard.
__device__ __forceinline__ float fast_exp2(float x) {
  float r;
  asm("v_exp_f32 %0, %1" : "=v"(r) : "v"(x));
  return r;
}

// async global->LDS, 16B per lane; LDS dest = wave-uniform base + lane*16.
__device__ __forceinline__ void gll16(const void* g, void* l) {
  __builtin_amdgcn_global_load_lds((const __attribute__((address_space(1))) void*)g,
                                   (__attribute__((address_space(3))) void*)l,
                                   16, 0, 0);
}

// 7-bit inverse K-row permutation (LDS row -> global key).
// row{c1,c0,t,q1,q0,r1,r0} -> key{c1,c0,q1,q0,t,r1,r0}.
__device__ __forceinline__ int kperm_inv7(int r) {
  return (r & 0x63) | ((r & 0x0C) << 1) | ((r & 0x10) >> 2);
}

// Fused prep: blocks [0,2048) cast x f32->bf16 (8/thread);
// [2048,5120) transpose+cast W_attn; [5120,6144) transpose+cast W_proj.
__global__ void prep_kernel(const float* __restrict__ x, BF16* __restrict__ xb,
                            const float* __restrict__ Wa, BF16* __restrict__ WaT,
                            const float* __restrict__ Wp, BF16* __restrict__ WpT) {
  __shared__ float tile[32][33];
  const int bx = blockIdx.x, tid = threadIdx.x;
  if (bx < 2048) {
    const int i = (bx * 256 + tid) * 8;
    const float4 a = *(const float4*)&x[i];
    const float4 b = *(const float4*)&x[i + 4];
    BF16 o[8];
    o[0] = __float2bfloat16(a.x); o[1] = __float2bfloat16(a.y);
    o[2] = __float2bfloat16(a.z); o[3] = __float2bfloat16(a.w);
    o[4] = __float2bfloat16(b.x); o[5] = __float2bfloat16(b.y);
    o[6] = __float2bfloat16(b.z); o[7] = __float2bfloat16(b.w);
    *(uint4*)&xb[i] = *(const uint4*)o;
    return;
  }
  const float* in; BF16* outT; int K, N, gx, gy;
  if (bx < 5120) {
    const int idx = bx - 2048;
    in = Wa; outT = WaT; K = 1024; N = 3072; gx = idx % 96; gy = idx / 96;
  } else {
    const int idx = bx - 5120;
    in = Wp; outT = WpT; K = 1024; N = 1024; gx = idx % 32; gy = idx / 32;
  }
  const int n0 = gx * 32, k0 = gy * 32;
  const int tx = tid & 31, ty = tid >> 5;
#pragma unroll
  for (int i = ty; i < 32; i += 8) tile[i][tx] = in[(size_t)(k0 + i) * N + (n0 + tx)];
  __syncthreads();
#pragma unroll
  for (int i = ty; i < 32; i += 8)
    outT[(size_t)(n0 + i) * K + (k0 + tx)] = __float2bfloat16(tile[tx][i]);
}

// C[m][n] = sum_k A[m][k]*Bt[n][k] + bias[n].  128x128 tile, BK=64, 2-phase.
// LDS granule-XOR swizzled via pre-swizzled global source (R11, 0 conflicts).
// MODE 0: scatter q/k [B,H,T,D] bf16 (q pre-scaled log2e/8), V transposed
// [B,H,D,T] (8B packed stores). MODE 1: f32 out.
template <int MODE>
__global__ __launch_bounds__(256) void gemm_bt(const BF16* __restrict__ A,
                                               const BF16* __restrict__ Bt,
                                               const float* __restrict__ bias,
                                               BF16* __restrict__ oq,
                                               BF16* __restrict__ ok,
                                               BF16* __restrict__ ov,
                                               float* __restrict__ fout,
                                               int Ndim, int Kdim) {
  __shared__ alignas(16) BF16 sA[128 * 64];
  __shared__ alignas(16) BF16 sB[128 * 64];
  const int tid = threadIdx.x;
  const int wave = tid >> 6, lane = tid & 63;
  const int quad = lane >> 4, l16 = lane & 15;
  const int wm = (wave >> 1) * 64, wn = (wave & 1) * 64;
  const int bm = blockIdx.y * 128, bn = blockIdx.x * 128;
  const int sw = l16 & 7;  // read-side swizzle key (= row&7 for row base%16==0)

  f32x4 acc[4][4];
#pragma unroll
  for (int i = 0; i < 4; ++i)
#pragma unroll
    for (int j = 0; j < 4; ++j) acc[i][j] = f32x4{0.f, 0.f, 0.f, 0.f};

  // Staging: wave stages rows wave*32 + s*8 + (lane>>3), s=0..3.
  const int srow = wave * 32 + (lane >> 3);
  const int sgl = (lane ^ (lane >> 3)) & 7;
  const BF16* gA0 = &A[(size_t)(bm + srow) * Kdim + sgl * 8];
  const BF16* gB0 = &Bt[(size_t)(bn + srow) * Kdim + sgl * 8];
  const size_t rstep8 = (size_t)8 * Kdim;

  for (int k0 = 0; k0 < Kdim; k0 += 64) {
    __syncthreads();  // WAR: all waves done reading previous tile
#pragma unroll
    for (int s = 0; s < 4; ++s) {
      gll16(gA0 + s * rstep8 + k0, &sA[wave * 2048 + s * 512]);
      gll16(gB0 + s * rstep8 + k0, &sB[wave * 2048 + s * 512]);
    }
    __syncthreads();  // compiler drains vmcnt(0) before barrier -> tile visible

#pragma unroll
    for (int h = 0; h < 2; ++h) {
      bf16x8 af[4], bf_[4];
#pragma unroll
      for (int i = 0; i < 4; ++i)
        af[i] = *(const bf16x8*)
            &sA[(wm + i * 16 + l16) * 64 + (((h * 4 + quad) ^ sw) << 3)];
#pragma unroll
      for (int j = 0; j < 4; ++j)
        bf_[j] = *(const bf16x8*)
            &sB[(wn + j * 16 + l16) * 64 + (((h * 4 + quad) ^ sw) << 3)];
#pragma unroll
      for (int i = 0; i < 4; ++i)
#pragma unroll
        for (int j = 0; j < 4; ++j) acc[i][j] = mfma16(af[i], bf_[j], acc[i][j]);
    }
  }

#pragma unroll
  for (int j = 0; j < 4; ++j) {
    const int gn = bn + wn + j * 16 + l16;
    const float bsv = bias[gn];
    if (MODE == 1) {
#pragma unroll
      for (int i = 0; i < 4; ++i)
#pragma unroll
        for (int r = 0; r < 4; ++r) {
          const int gm = bm + wm + i * 16 + quad * 4 + r;
          fout[(size_t)gm * Ndim + gn] = acc[i][j][r] + bsv;
        }
    } else {
      // which is wave-uniform per j: gn span is 16-aligned, never crosses 1024.
      const int which = (bn + wn + j * 16) >> 10;
      const int c = gn & 1023;
      const int hh = c >> 6, dd = c & 63;
#pragma unroll
      for (int i = 0; i < 4; ++i) {
        const int gm0 = bm + wm + i * 16 + quad * 4;  // 4-aligned: bb/tk0 uniform over r
        const int bb = gm0 >> 11, tk0 = gm0 & 2047;
        const size_t bh = (size_t)(bb * Hh + hh);
        if (which == 2) {
          // V: transposed [B,H,D,T]; r-accs are contiguous t -> one 8B store.
          BF16 tmp[4];
#pragma unroll
          for (int r = 0; r < 4; ++r) tmp[r] = __float2bfloat16(acc[i][j][r] + bsv);
          *(uint2*)&ov[(bh * Dd + dd) * Tt + tk0] = *(const uint2*)tmp;
        } else {
          BF16* dst = (which == 0) ? oq : ok;
          const float scale = (which == 0) ? Q_SCALE : 1.0f;
#pragma unroll
          for (int r = 0; r < 4; ++r)
            dst[(bh * Tt + tk0 + r) * Dd + dd] =
                __float2bfloat16((acc[i][j][r] + bsv) * scale);
        }
      }
    }
  }
}

// Causal flash attention, KVBLK=128, 2-wave blocks, 32 q-rows/wave.
// Block = one 64-row q-strip s (waves own rows wave*32..+31, two 16-row
// groups each); nt = (s>>1)+1 tiles of 128 keys. K/V frag LDS reads feed
// BOTH q-groups (reads/MFMA halved). 1024 blocks, long-first, 2-of-4/CU
// resident (refill slack). K [128 perm rows][64 d] XOR-8; V^T [64 d][128 key]
// XOR-16; gll16 staging (16/thread/tile) from pre-swizzled global sources.
__global__ __launch_bounds__(128) void attn_kernel(const BF16* __restrict__ qg,
                                                   const BF16* __restrict__ kg,
                                                   const BF16* __restrict__ vtg,
                                                   BF16* __restrict__ yb) {
  __shared__ alignas(16) BF16 sK[2 * 8192];  // [buf][perm_key 128][d 64]
  __shared__ alignas(16) BF16 sV[2 * 8192];  // [buf][d 64][key 128]
  const int id = blockIdx.x;
  const int xcd = id & 7, local = id >> 3;      // blockIdx%8 round-robins XCDs
  const int bh = xcd * 4 + (local & 3);         // 4 (b,h) per XCD: 2MB K/V in L2
  const int s = 31 - (local >> 2);              // 64-row strip, long first
  const int b = bh >> 4, h = bh & 15;
  const int tid = threadIdx.x;
  const int wave = tid >> 6, lane = tid & 63;
  const int quad = lane >> 4, l16 = lane & 15;
  const size_t base = ((size_t)(b * Hh + h)) * Tt * Dd;
  const int qrow0 = s * 64 + wave * 32;  // wave's 32 rows (two 16-row groups)
  const int sw = l16 & 7;

  // Q fragments for both 16-row groups (B-operand: lane n=l16 -> row +qg2*16+l16)
  bf16x8 qf[2][2];
#pragma unroll
  for (int qg2 = 0; qg2 < 2; ++qg2) {
    const size_t off = base + (size_t)(qrow0 + qg2 * 16 + l16) * Dd;
    qf[qg2][0] = *(const bf16x8*)&qg[off + quad * 8];
    qf[qg2][1] = *(const bf16x8*)&qg[off + 32 + quad * 8];
  }

  bf16x8 ones8;
#pragma unroll
  for (int j = 0; j < 8; ++j) ones8[j] = (__bf16)1.0f;

  f32x4 o0[4], o1[4], oL0, oL1;
#pragma unroll
  for (int i = 0; i < 4; ++i) {
    o0[i] = f32x4{0.f, 0.f, 0.f, 0.f};
    o1[i] = f32x4{0.f, 0.f, 0.f, 0.f};
  }
  oL0 = f32x4{0.f, 0.f, 0.f, 0.f};
  oL1 = f32x4{0.f, 0.f, 0.f, 0.f};

  const f32x4 cbias = f32x4{-EXP2_BIAS, -EXP2_BIAS, -EXP2_BIAS, -EXP2_BIAS};

  // Staging (per thread, 8 K + 8 V gll16 per tile; 128 threads cover 16KB+16KB).
  // K instr i: row = wave*64 + i*8 + (lane>>3); phys gran lane&7;
  //            src gran (lane^(lane>>3))&7; src key kperm_inv7(row).
  // V instr i: d = wave*32 + i*4 + (lane>>4); phys gran lane&15;
  //            src gran (lane&15) ^ ((i*4 + (lane>>4)) & 15)  [d&15 folded].
  const int sgk = (lane ^ (lane >> 3)) & 7;
  const BF16* pk[8];
  const BF16* pv[8];
#pragma unroll
  for (int i = 0; i < 8; ++i) {
    const int krow = wave * 64 + i * 8 + (lane >> 3);
    pk[i] = &kg[base + (size_t)kperm_inv7(krow) * Dd + sgk * 8];
    const int vd = wave * 32 + i * 4 + (lane >> 4);
    const int vg = (lane & 15) ^ ((i * 4 + (lane >> 4)) & 15);
    pv[i] = &vtg[base + (size_t)vd * Tt + vg * 8];
  }
  const int dstb = wave * 4096;  // elem base per wave (K and V identical)

#define STAGE(buf, jt_)                                                  \
  do {                                                                   \
    const size_t ko_ = (size_t)(jt_) * 8192;  /* 128 keys * 64 d */      \
    const int vo_ = (jt_) * 128;                                         \
    _Pragma("unroll") for (int i_ = 0; i_ < 8; ++i_) {                   \
      gll16(pk[i_] + ko_, &sK[(buf) * 8192 + dstb + i_ * 512]);          \
      gll16(pv[i_] + vo_, &sV[(buf) * 8192 + dstb + i_ * 512]);          \
    }                                                                    \
  } while (0)

  const int nt = (s >> 1) + 1;  // tiles of 128 keys
  STAGE(0, 0);

  for (int jt = 0; jt < nt; ++jt) {
    asm volatile("s_waitcnt vmcnt(0)" ::: "memory");
    __builtin_amdgcn_s_barrier();
    const BF16* sKb = &sK[(jt & 1) * 8192];
    const BF16* sVb = &sV[(jt & 1) * 8192];
    if (jt < nt - 1) STAGE((jt + 1) & 1, jt + 1);

    // S^T tile tt (0..7): A = perm K rows tt*16+l16 (read ONCE, feeds both
    // q-groups). C-layout: col l16 = q (within group), row quad*4+r -> key
    // kc = jt*128 + (tt>>1)*32 + quad*8 + (tt&1)*4 + r. C-init = -EXP2_BIAS.
    f32x4 sS0[8], sS1[8];
    __builtin_amdgcn_s_setprio(1);
#pragma unroll
    for (int tt = 0; tt < 8; ++tt) {
      const bf16x8 kf0 =
          *(const bf16x8*)&sKb[(tt * 16 + l16) * 64 + ((quad ^ sw) << 3)];
      const bf16x8 kf1 =
          *(const bf16x8*)&sKb[(tt * 16 + l16) * 64 + (((4 + quad) ^ sw) << 3)];
      sS0[tt] = mfma16(kf0, qf[0][0], cbias);
      sS0[tt] = mfma16(kf1, qf[0][1], sS0[tt]);
      sS1[tt] = mfma16(kf0, qf[1][0], cbias);
      sS1[tt] = mfma16(kf1, qf[1][1], sS1[tt]);
    }
    __builtin_amdgcn_s_setprio(0);

    if (jt == nt - 1) {  // boundary tile: causal mask (per q-group)
      const int kb = jt * 128;
      const int q0 = qrow0 + l16, q1 = qrow0 + 16 + l16;
#pragma unroll
      for (int tt = 0; tt < 8; ++tt) {
        const int kc0 = kb + (tt >> 1) * 32 + quad * 8 + (tt & 1) * 4;
#pragma unroll
        for (int r = 0; r < 4; ++r) {
          if (kc0 + r > q0) sS0[tt][r] = NEG_INF;
          if (kc0 + r > q1) sS1[tt][r] = NEG_INF;
        }
      }
    }

    // p = v_exp_f32(S) packed into K=32 A-frags (kc = cc*32 + quad*8 + j)
    bf16x8 pf0[4], pf1[4];
#pragma unroll
    for (int cc = 0; cc < 4; ++cc)
#pragma unroll
      for (int j = 0; j < 8; ++j) {
        pf0[cc][j] = (__bf16)fast_exp2(sS0[cc * 2 + (j >> 2)][j & 3]);
        pf1[cc][j] = (__bf16)fast_exp2(sS1[cc * 2 + (j >> 2)][j & 3]);
      }

    // PV + rowsum, 4x K=32. vb read ONCE, feeds both q-groups' MFMAs.
    __builtin_amdgcn_s_setprio(1);
#pragma unroll
    for (int cc = 0; cc < 4; ++cc) {
#pragma unroll
      for (int dt = 0; dt < 4; ++dt) {
        const bf16x8 vb = *(const bf16x8*)
            &sVb[(dt * 16 + l16) * 128 + ((((cc * 4 + quad) ^ l16) & 15) << 3)];
        o0[dt] = mfma16(pf0[cc], vb, o0[dt]);
        o1[dt] = mfma16(pf1[cc], vb, o1[dt]);
      }
      oL0 = mfma16(pf0[cc], ones8, oL0);
      oL1 = mfma16(pf1[cc], ones8, oL1);
    }
    __builtin_amdgcn_s_setprio(0);
  }
#undef STAGE

  // epilogue: C-layout row quad*4+r = q (within group), col dt*16+l16 = d
#pragma unroll
  for (int r = 0; r < 4; ++r) {
    const float inv0 = 1.0f / oL0[r];
    const float inv1 = 1.0f / oL1[r];
    const int trow0 = qrow0 + quad * 4 + r;
    const int trow1 = trow0 + 16;
#pragma unroll
    for (int dt = 0; dt < 4; ++dt) {
      yb[((size_t)(b * Tt + trow0)) * Cc + h * Dd + dt * 16 + l16] =
          __float2bfloat16(o0[dt][r] * inv0);
      yb[((size_t)(b * Tt + trow1)) * Cc + h * Dd + dt * 16 + l16] =
          __float2bfloat16(o1[dt][r] * inv1);
    }
  }
}

extern "C" void kernel_launch(void* const* d_in, const int* in_sizes, int n_in,
                              void* d_out, int out_size, void* d_ws, size_t ws_size,
                              hipStream_t stream) {
  (void)in_sizes; (void)n_in; (void)out_size; (void)ws_size;
  const float* x      = (const float*)d_in[0];
  const float* W_attn = (const float*)d_in[1];
  const float* b_attn = (const float*)d_in[2];
  const float* W_proj = (const float*)d_in[3];
  const float* b_proj = (const float*)d_in[4];
  float* out = (float*)d_out;

  constexpr size_t SZ_WA = (size_t)3072 * 1024;
  constexpr size_t SZ_WP = (size_t)1024 * 1024;
  constexpr size_t SZ_X  = (size_t)4096 * 1024;
  constexpr size_t SZ_T  = (size_t)Bb * Hh * Tt * Dd;

  BF16* ws   = (BF16*)d_ws;
  BF16* wtAb = ws;
  BF16* wtPb = wtAb + SZ_WA;
  BF16* xb   = wtPb + SZ_WP;
  BF16* q    = xb + SZ_X;
  BF16* k    = q + SZ_T;
  BF16* vt   = k + SZ_T;
  BF16* yb   = vt + SZ_T;

  prep_kernel<<<dim3(6144), 256, 0, stream>>>(x, xb, W_attn, wtAb, W_proj, wtPb);
  gemm_bt<0><<<dim3(24, 32), 256, 0, stream>>>(xb, wtAb, b_attn, q, k, vt, nullptr,
                                               3072, 1024);
  attn_kernel<<<dim3(1024), 128, 0, stream>>>(q, k, vt, yb);
  gemm_bt<1><<<dim3(8, 32), 256, 0, stream>>>(yb, wtPb, b_proj, nullptr, nullptr,
                                              nullptr, out, 1024, 1024);
}

// Round 10
// 167.386 us; speedup vs baseline: 1.0902x; 1.0902x over previous
//
#include <hip/hip_runtime.h>
#include <hip/hip_bf16.h>

// B=2, T=2048, C=1024, H=16, D=64. Inputs/outputs FLOAT32; compute bf16 MFMA.
// R17: attn = R14 structure (4 waves x 16 q-rows, 64-row strip, KVBLK=128,
// 1024 blocks — best measured) + T15 skew: iter jt computes
//   exp/PV of tile jt-1 (VALU+MFMA)  ||  QK of tile jt (MFMA)
// so the exp VALU stream is data-independent of the QK MFMA stream in the
// same straight-line block (first/last iters peeled). K(t) staged iter t-1
// buf t&1; V(t) staged iter t buf t&1, read iter t+1; WAR by top barrier,
// RAW by per-wave vmcnt(0). R15/R16 read-sharing reverted (TLP loss > gain).
// gemm_bt/prep unchanged (R11 known-good).

typedef __bf16 bf16x8 __attribute__((ext_vector_type(8)));
typedef float  f32x4  __attribute__((ext_vector_type(4)));
#define BF16 __hip_bfloat16

constexpr int Bb = 2, Tt = 2048, Cc = 1024, Hh = 16, Dd = 64;
constexpr float NEG_INF = -1e30f;
constexpr float Q_SCALE = 0.18033688011112042f;   // (1/8) * log2(e)
constexpr float EXP2_BIAS = 17.312340490667562f;  // 12 * log2(e)

__device__ __forceinline__ f32x4 mfma16(bf16x8 a, bf16x8 b, f32x4 c) {
  return __builtin_amdgcn_mfma_f32_16x16x32_bf16(a, b, c, 0, 0, 0);
}

// raw v_exp_f32 (exp2): 1 trans instr, no OCML denormal guard.
__device__ __forceinline__ float fast_exp2(float x) {
  float r;
  asm("v_exp_f32 %0, %1" : "=v"(r) : "v"(x));
  return r;
}

// async global->LDS, 16B per lane; LDS dest = wave-uniform base + lane*16.
__device__ __forceinline__ void gll16(const void* g, void* l) {
  __builtin_amdgcn_global_load_lds((const __attribute__((address_space(1))) void*)g,
                                   (__attribute__((address_space(3))) void*)l,
                                   16, 0, 0);
}

// 7-bit inverse K-row permutation (LDS row -> global key).
// row{c1,c0,t,q1,q0,r1,r0} -> key{c1,c0,q1,q0,t,r1,r0}.
__device__ __forceinline__ int kperm_inv7(int r) {
  return (r & 0x63) | ((r & 0x0C) << 1) | ((r & 0x10) >> 2);
}

// Fused prep: blocks [0,2048) cast x f32->bf16 (8/thread);
// [2048,5120) transpose+cast W_attn; [5120,6144) transpose+cast W_proj.
__global__ void prep_kernel(const float* __restrict__ x, BF16* __restrict__ xb,
                            const float* __restrict__ Wa, BF16* __restrict__ WaT,
                            const float* __restrict__ Wp, BF16* __restrict__ WpT) {
  __shared__ float tile[32][33];
  const int bx = blockIdx.x, tid = threadIdx.x;
  if (bx < 2048) {
    const int i = (bx * 256 + tid) * 8;
    const float4 a = *(const float4*)&x[i];
    const float4 b = *(const float4*)&x[i + 4];
    BF16 o[8];
    o[0] = __float2bfloat16(a.x); o[1] = __float2bfloat16(a.y);
    o[2] = __float2bfloat16(a.z); o[3] = __float2bfloat16(a.w);
    o[4] = __float2bfloat16(b.x); o[5] = __float2bfloat16(b.y);
    o[6] = __float2bfloat16(b.z); o[7] = __float2bfloat16(b.w);
    *(uint4*)&xb[i] = *(const uint4*)o;
    return;
  }
  const float* in; BF16* outT; int K, N, gx, gy;
  if (bx < 5120) {
    const int idx = bx - 2048;
    in = Wa; outT = WaT; K = 1024; N = 3072; gx = idx % 96; gy = idx / 96;
  } else {
    const int idx = bx - 5120;
    in = Wp; outT = WpT; K = 1024; N = 1024; gx = idx % 32; gy = idx / 32;
  }
  const int n0 = gx * 32, k0 = gy * 32;
  const int tx = tid & 31, ty = tid >> 5;
#pragma unroll
  for (int i = ty; i < 32; i += 8) tile[i][tx] = in[(size_t)(k0 + i) * N + (n0 + tx)];
  __syncthreads();
#pragma unroll
  for (int i = ty; i < 32; i += 8)
    outT[(size_t)(n0 + i) * K + (k0 + tx)] = __float2bfloat16(tile[tx][i]);
}

// C[m][n] = sum_k A[m][k]*Bt[n][k] + bias[n].  128x128 tile, BK=64, 2-phase.
// LDS granule-XOR swizzled via pre-swizzled global source (R11, 0 conflicts).
// MODE 0: scatter q/k [B,H,T,D] bf16 (q pre-scaled log2e/8), V transposed
// [B,H,D,T] (8B packed stores). MODE 1: f32 out.
template <int MODE>
__global__ __launch_bounds__(256) void gemm_bt(const BF16* __restrict__ A,
                                               const BF16* __restrict__ Bt,
                                               const float* __restrict__ bias,
                                               BF16* __restrict__ oq,
                                               BF16* __restrict__ ok,
                                               BF16* __restrict__ ov,
                                               float* __restrict__ fout,
                                               int Ndim, int Kdim) {
  __shared__ alignas(16) BF16 sA[128 * 64];
  __shared__ alignas(16) BF16 sB[128 * 64];
  const int tid = threadIdx.x;
  const int wave = tid >> 6, lane = tid & 63;
  const int quad = lane >> 4, l16 = lane & 15;
  const int wm = (wave >> 1) * 64, wn = (wave & 1) * 64;
  const int bm = blockIdx.y * 128, bn = blockIdx.x * 128;
  const int sw = l16 & 7;  // read-side swizzle key (= row&7 for row base%16==0)

  f32x4 acc[4][4];
#pragma unroll
  for (int i = 0; i < 4; ++i)
#pragma unroll
    for (int j = 0; j < 4; ++j) acc[i][j] = f32x4{0.f, 0.f, 0.f, 0.f};

  // Staging: wave stages rows wave*32 + s*8 + (lane>>3), s=0..3.
  const int srow = wave * 32 + (lane >> 3);
  const int sgl = (lane ^ (lane >> 3)) & 7;
  const BF16* gA0 = &A[(size_t)(bm + srow) * Kdim + sgl * 8];
  const BF16* gB0 = &Bt[(size_t)(bn + srow) * Kdim + sgl * 8];
  const size_t rstep8 = (size_t)8 * Kdim;

  for (int k0 = 0; k0 < Kdim; k0 += 64) {
    __syncthreads();  // WAR: all waves done reading previous tile
#pragma unroll
    for (int s = 0; s < 4; ++s) {
      gll16(gA0 + s * rstep8 + k0, &sA[wave * 2048 + s * 512]);
      gll16(gB0 + s * rstep8 + k0, &sB[wave * 2048 + s * 512]);
    }
    __syncthreads();  // compiler drains vmcnt(0) before barrier -> tile visible

#pragma unroll
    for (int h = 0; h < 2; ++h) {
      bf16x8 af[4], bf_[4];
#pragma unroll
      for (int i = 0; i < 4; ++i)
        af[i] = *(const bf16x8*)
            &sA[(wm + i * 16 + l16) * 64 + (((h * 4 + quad) ^ sw) << 3)];
#pragma unroll
      for (int j = 0; j < 4; ++j)
        bf_[j] = *(const bf16x8*)
            &sB[(wn + j * 16 + l16) * 64 + (((h * 4 + quad) ^ sw) << 3)];
#pragma unroll
      for (int i = 0; i < 4; ++i)
#pragma unroll
        for (int j = 0; j < 4; ++j) acc[i][j] = mfma16(af[i], bf_[j], acc[i][j]);
    }
  }

#pragma unroll
  for (int j = 0; j < 4; ++j) {
    const int gn = bn + wn + j * 16 + l16;
    const float bsv = bias[gn];
    if (MODE == 1) {
#pragma unroll
      for (int i = 0; i < 4; ++i)
#pragma unroll
        for (int r = 0; r < 4; ++r) {
          const int gm = bm + wm + i * 16 + quad * 4 + r;
          fout[(size_t)gm * Ndim + gn] = acc[i][j][r] + bsv;
        }
    } else {
      // which is wave-uniform per j: gn span is 16-aligned, never crosses 1024.
      const int which = (bn + wn + j * 16) >> 10;
      const int c = gn & 1023;
      const int hh = c >> 6, dd = c & 63;
#pragma unroll
      for (int i = 0; i < 4; ++i) {
        const int gm0 = bm + wm + i * 16 + quad * 4;  // 4-aligned: bb/tk0 uniform over r
        const int bb = gm0 >> 11, tk0 = gm0 & 2047;
        const size_t bh = (size_t)(bb * Hh + hh);
        if (which == 2) {
          // V: transposed [B,H,D,T]; r-accs are contiguous t -> one 8B store.
          BF16 tmp[4];
#pragma unroll
          for (int r = 0; r < 4; ++r) tmp[r] = __float2bfloat16(acc[i][j][r] + bsv);
          *(uint2*)&ov[(bh * Dd + dd) * Tt + tk0] = *(const uint2*)tmp;
        } else {
          BF16* dst = (which == 0) ? oq : ok;
          const float scale = (which == 0) ? Q_SCALE : 1.0f;
#pragma unroll
          for (int r = 0; r < 4; ++r)
            dst[(bh * Tt + tk0 + r) * Dd + dd] =
                __float2bfloat16((acc[i][j][r] + bsv) * scale);
        }
      }
    }
  }
}

// Causal flash attention, KVBLK=128, T15-skewed pipeline.
// Block = one 64-row q-strip s (4 waves x 16 rows); nt = (s+2)>>1 tiles of
// 128 keys; iters jt=0..nt. Iter jt: {vmcnt(0); barrier; stage V(jt),K(jt+1);
// exp(sS[jt-1]) VALU || QK(jt) MFMA; mask@nt-1; PV(jt-1)}.
// K [128 perm rows][64 d] XOR-8; V^T [64 d][128 keys] XOR-16; gll16 staging
// from pre-swizzled global; p = v_exp_f32(S + C-in bias); q pre-scaled.
__global__ __launch_bounds__(256) void attn_kernel(const BF16* __restrict__ qg,
                                                   const BF16* __restrict__ kg,
                                                   const BF16* __restrict__ vtg,
                                                   BF16* __restrict__ yb) {
  __shared__ alignas(16) BF16 sK[2 * 8192];  // [buf][perm_key 128][d 64]
  __shared__ alignas(16) BF16 sV[2 * 8192];  // [buf][d 64][key 128]
  const int id = blockIdx.x;
  const int xcd = id & 7, local = id >> 3;      // blockIdx%8 round-robins XCDs
  const int bh = xcd * 4 + (local & 3);         // 4 (b,h) per XCD: 2MB K/V in L2
  const int s = 31 - (local >> 2);              // 64-row strip, long first
  const int b = bh >> 4, h = bh & 15;
  const int tid = threadIdx.x;
  const int wave = tid >> 6, lane = tid & 63;
  const int quad = lane >> 4, l16 = lane & 15;
  const size_t base = ((size_t)(b * Hh + h)) * Tt * Dd;
  const int qrow0 = s * 64 + wave * 16;
  const int sw = l16 & 7;

  // Q fragment (B-operand: lane n=l16 holds Q[qrow0+l16][k=quad*8+j])
  bf16x8 qf0, qf1;
  {
    const size_t off = base + (size_t)(qrow0 + l16) * Dd;
    qf0 = *(const bf16x8*)&qg[off + quad * 8];
    qf1 = *(const bf16x8*)&qg[off + 32 + quad * 8];
  }

  bf16x8 ones8;
#pragma unroll
  for (int j = 0; j < 8; ++j) ones8[j] = (__bf16)1.0f;

  f32x4 o[4], oL;
#pragma unroll
  for (int i = 0; i < 4; ++i) o[i] = f32x4{0.f, 0.f, 0.f, 0.f};
  oL = f32x4{0.f, 0.f, 0.f, 0.f};

  const f32x4 cbias = f32x4{-EXP2_BIAS, -EXP2_BIAS, -EXP2_BIAS, -EXP2_BIAS};

  // Staging (per thread, 4 K + 4 V gll16 per tile) — R14 layout.
  const int t = tid;
  const int sgk = (t ^ (t >> 3)) & 7;
  const int sgv = (t ^ (t >> 4)) & 15;
  const BF16* pk[4];
  const BF16* pv[4];
#pragma unroll
  for (int i = 0; i < 4; ++i) {
    pk[i] = &kg[base + (size_t)kperm_inv7(i * 32 + (t >> 3)) * Dd + sgk * 8];
    pv[i] = &vtg[base + (size_t)(i * 16 + (t >> 4)) * Tt + sgv * 8];
  }

#define STAGE_K(buf, tt_)                                            \
  do {                                                               \
    const size_t ko_ = (size_t)(tt_) * 8192;                         \
    _Pragma("unroll") for (int i_ = 0; i_ < 4; ++i_)                 \
        gll16(pk[i_] + ko_, &sK[(buf) * 8192 + i_ * 2048 + t * 8]);  \
  } while (0)
#define STAGE_V(buf, tt_)                                            \
  do {                                                               \
    const int vo_ = (tt_) * 128;                                     \
    _Pragma("unroll") for (int i_ = 0; i_ < 4; ++i_)                 \
        gll16(pv[i_] + vo_, &sV[(buf) * 8192 + i_ * 2048 + t * 8]);  \
  } while (0)

#define QK_TILE(jt_)                                                        \
  do {                                                                      \
    const BF16* sKb_ = &sK[((jt_) & 1) * 8192];                             \
    __builtin_amdgcn_s_setprio(1);                                          \
    _Pragma("unroll") for (int tt = 0; tt < 8; ++tt) {                      \
      const bf16x8 kf0 =                                                    \
          *(const bf16x8*)&sKb_[(tt * 16 + l16) * 64 + ((quad ^ sw) << 3)]; \
      const bf16x8 kf1 = *(const bf16x8*)                                   \
          &sKb_[(tt * 16 + l16) * 64 + (((4 + quad) ^ sw) << 3)];           \
      sS[tt] = mfma16(kf0, qf0, cbias);                                     \
      sS[tt] = mfma16(kf1, qf1, sS[tt]);                                    \
    }                                                                       \
    __builtin_amdgcn_s_setprio(0);                                          \
  } while (0)

#define MASK_TILE(jt_)                                                  \
  do {                                                                  \
    const int kb_ = (jt_) * 128;                                        \
    const int q_ = qrow0 + l16;                                         \
    _Pragma("unroll") for (int tt = 0; tt < 8; ++tt) {                  \
      const int kc0 = kb_ + (tt >> 1) * 32 + quad * 8 + (tt & 1) * 4;   \
      _Pragma("unroll") for (int r = 0; r < 4; ++r)                     \
          if (kc0 + r > q_) sS[tt][r] = NEG_INF;                        \
    }                                                                   \
  } while (0)

#define EXP_P()                                                         \
  do {                                                                  \
    _Pragma("unroll") for (int cc = 0; cc < 4; ++cc)                    \
        _Pragma("unroll") for (int j = 0; j < 8; ++j)                   \
            pf[cc][j] = (__bf16)fast_exp2(sS[cc * 2 + (j >> 2)][j & 3]); \
  } while (0)

#define PV_TILE(jt_)                                                          \
  do {                                                                        \
    const BF16* sVb_ = &sV[((jt_) & 1) * 8192];                               \
    __builtin_amdgcn_s_setprio(1);                                            \
    _Pragma("unroll") for (int cc = 0; cc < 4; ++cc) {                        \
      _Pragma("unroll") for (int dt = 0; dt < 4; ++dt) {                      \
        const bf16x8 vb = *(const bf16x8*)                                    \
            &sVb_[(dt * 16 + l16) * 128 +                                     \
                  ((((cc * 4 + quad) ^ l16) & 15) << 3)];                     \
        o[dt] = mfma16(pf[cc], vb, o[dt]);                                    \
      }                                                                       \
      oL = mfma16(pf[cc], ones8, oL);                                         \
    }                                                                         \
    __builtin_amdgcn_s_setprio(0);                                            \
  } while (0)

  const int nt = (s + 2) >> 1;  // tiles of 128 keys
  f32x4 sS[8];
  bf16x8 pf[4];

  // prologue: K(0) in flight
  STAGE_K(0, 0);

  // iter 0: QK(0) only
  asm volatile("s_waitcnt vmcnt(0)" ::: "memory");
  __builtin_amdgcn_s_barrier();
  STAGE_V(0, 0);
  if (nt > 1) STAGE_K(1, 1);
  QK_TILE(0);
  if (nt == 1) MASK_TILE(0);

  // main iters 1..nt-1: exp/PV(jt-1) || QK(jt)
  for (int jt = 1; jt < nt; ++jt) {
    asm volatile("s_waitcnt vmcnt(0)" ::: "memory");
    __builtin_amdgcn_s_barrier();
    STAGE_V(jt & 1, jt);
    if (jt + 1 < nt) STAGE_K((jt + 1) & 1, jt + 1);
    EXP_P();       // VALU, reads sS of tile jt-1 (independent of QK below)
    QK_TILE(jt);   // MFMA, overlaps EXP_P in the same straight-line block
    if (jt == nt - 1) MASK_TILE(jt);
    PV_TILE(jt - 1);
  }

  // final iter nt: exp/PV of tile nt-1
  asm volatile("s_waitcnt vmcnt(0)" ::: "memory");
  __builtin_amdgcn_s_barrier();
  EXP_P();
  PV_TILE(nt - 1);

#undef STAGE_K
#undef STAGE_V
#undef QK_TILE
#undef MASK_TILE
#undef EXP_P
#undef PV_TILE

  // epilogue: C-layout row quad*4+r = q, col dt*16+l16 = d
#pragma unroll
  for (int r = 0; r < 4; ++r) {
    const float inv = 1.0f / oL[r];
    const int trow = qrow0 + quad * 4 + r;
#pragma unroll
    for (int dt = 0; dt < 4; ++dt)
      yb[((size_t)(b * Tt + trow)) * Cc + h * Dd + dt * 16 + l16] =
          __float2bfloat16(o[dt][r] * inv);
  }
}

extern "C" void kernel_launch(void* const* d_in, const int* in_sizes, int n_in,
                              void* d_out, int out_size, void* d_ws, size_t ws_size,
                              hipStream_t stream) {
  (void)in_sizes; (void)n_in; (void)out_size; (void)ws_size;
  const float* x      = (const float*)d_in[0];
  const float* W_attn = (const float*)d_in[1];
  const float* b_attn = (const float*)d_in[2];
  const float* W_proj = (const float*)d_in[3];
  const float* b_proj = (const float*)d_in[4];
  float* out = (float*)d_out;

  constexpr size_t SZ_WA = (size_t)3072 * 1024;
  constexpr size_t SZ_WP = (size_t)1024 * 1024;
  constexpr size_t SZ_X  = (size_t)4096 * 1024;
  constexpr size_t SZ_T  = (size_t)Bb * Hh * Tt * Dd;

  BF16* ws   = (BF16*)d_ws;
  BF16* wtAb = ws;
  BF16* wtPb = wtAb + SZ_WA;
  BF16* xb   = wtPb + SZ_WP;
  BF16* q    = xb + SZ_X;
  BF16* k    = q + SZ_T;
  BF16* vt   = k + SZ_T;
  BF16* yb   = vt + SZ_T;

  prep_kernel<<<dim3(6144), 256, 0, stream>>>(x, xb, W_attn, wtAb, W_proj, wtPb);
  gemm_bt<0><<<dim3(24, 32), 256, 0, stream>>>(xb, wtAb, b_attn, q, k, vt, nullptr,
                                               3072, 1024);
  attn_kernel<<<dim3(1024), 256, 0, stream>>>(q, k, vt, yb);
  gemm_bt<1><<<dim3(8, 32), 256, 0, stream>>>(yb, wtPb, b_proj, nullptr, nullptr,
                                              nullptr, out, 1024, 1024);
}